// Round 13
// baseline (1792.010 us; speedup 1.0000x reference)
//
#include <hip/hip_runtime.h>
#include <hip/hip_bf16.h>

#define D_DIM 2048
#define E_DIM 8

typedef __attribute__((ext_vector_type(8))) short short8;
typedef __attribute__((ext_vector_type(4))) float f32x4;

__device__ __forceinline__ unsigned short f2bf(float f) {
  union { float f; unsigned int u; } v; v.f = f;
  unsigned int u = v.u;
  u += 0x7FFFu + ((u >> 16) & 1u);   // round-to-nearest-even
  return (unsigned short)(u >> 16);
}

__device__ __forceinline__ void async_copy16(const void* g, void* l) {
  __builtin_amdgcn_global_load_lds((const __attribute__((address_space(1))) void*)g,
                                   (__attribute__((address_space(3))) void*)l,
                                   16, 0, 0);
}

// ---------------- transpose f32 -> bf16 (with zero pad) ----------------
__global__ void k_transpose_bf16(const float* __restrict__ in, int in_rows, int in_cols,
                                 int in_ld, unsigned short* __restrict__ out, int out_rows) {
  __shared__ float tile[32][33];
  const int tx = threadIdx.x;  // 0..31
  const int ty = threadIdx.y;  // 0..7
  const int c = blockIdx.x * 32 + tx;
  #pragma unroll
  for (int i = 0; i < 4; ++i) {
    const int r = blockIdx.y * 32 + ty + i * 8;
    float vv = 0.0f;
    if (r < in_rows && c < in_cols) vv = in[(size_t)r * in_ld + c];
    tile[ty + i * 8][tx] = vv;
  }
  __syncthreads();
  const int oc = blockIdx.y * 32 + tx;   // = original row
  #pragma unroll
  for (int i = 0; i < 4; ++i) {
    const int orow = blockIdx.x * 32 + ty + i * 8;  // = original col (padded)
    if (orow < out_rows && oc < in_rows)
      out[(size_t)orow * in_rows + oc] = f2bf(tile[tx][ty + i * 8]);
  }
}

// ---------------- pad-copy f32 -> bf16 (row-major, pad cols with 0) ----------------
__global__ void k_pad_bf16(const float* __restrict__ in, unsigned short* __restrict__ out,
                           int rows, int cols, int cols_pad) {
  long long idx = (long long)blockIdx.x * blockDim.x + threadIdx.x;
  const long long total = (long long)rows * cols_pad;
  const long long stride = (long long)gridDim.x * blockDim.x;
  for (; idx < total; idx += stride) {
    const int r = (int)(idx / cols_pad);
    const int c = (int)(idx % cols_pad);
    out[idx] = (c < cols) ? f2bf(in[(size_t)r * cols + c]) : (unsigned short)0;
  }
}

// ---------------- u1 = U @ Wg1  (f32, one wave per output row d) ----------------
__global__ void k_u1(const float* __restrict__ U, const float* __restrict__ Wg1,
                     float* __restrict__ u1, int D, int k) {
  const int w = threadIdx.x >> 6;
  const int lane = threadIdx.x & 63;
  const int d = blockIdx.x * 4 + w;
  if (d >= D) return;
  const float* row = U + (size_t)d * k;
  float s = 0.0f;
  for (int j = lane; j < k; j += 64) s += row[j] * Wg1[j];
  #pragma unroll
  for (int off = 32; off; off >>= 1) s += __shfl_xor(s, off);
  if (lane == 0) u1[d] = s;
}

// ---------------- fused cvt+gate: xb = bf16(x); g8 = softmax((x.u1)*Wg2) ----------
__global__ void k_cvtgate(const float* __restrict__ x,
                          unsigned short* __restrict__ xb,
                          const float* __restrict__ u1, const float* __restrict__ Wg2,
                          float* __restrict__ g8, int Nrows) {
  const int w = threadIdx.x >> 6;
  const int lane = threadIdx.x & 63;
  const int row = blockIdx.x * 4 + w;
  if (row >= Nrows) return;
  const float* xr = x + (size_t)row * D_DIM;
  unsigned short* xo = xb + (size_t)row * D_DIM;
  float s = 0.0f;
  #pragma unroll
  for (int t = 0; t < D_DIM / 512; ++t) {
    const int base = (t * 64 + lane) * 8;
    float4 a = *(const float4*)(xr + base);
    float4 b = *(const float4*)(xr + base + 4);
    float4 ua = *(const float4*)(u1 + base);
    float4 ub = *(const float4*)(u1 + base + 4);
    s += a.x * ua.x + a.y * ua.y + a.z * ua.z + a.w * ua.w +
         b.x * ub.x + b.y * ub.y + b.z * ub.z + b.w * ub.w;
    short8 r;
    r[0] = (short)f2bf(a.x); r[1] = (short)f2bf(a.y);
    r[2] = (short)f2bf(a.z); r[3] = (short)f2bf(a.w);
    r[4] = (short)f2bf(b.x); r[5] = (short)f2bf(b.y);
    r[6] = (short)f2bf(b.z); r[7] = (short)f2bf(b.w);
    *(short8*)(xo + base) = r;
  }
  #pragma unroll
  for (int off = 32; off; off >>= 1) s += __shfl_xor(s, off);
  if (lane == 0) {
    float lg[E_DIM], mx = -INFINITY;
    #pragma unroll
    for (int e = 0; e < E_DIM; ++e) { lg[e] = s * Wg2[e]; mx = fmaxf(mx, lg[e]); }
    float Z = 0.0f;
    #pragma unroll
    for (int e = 0; e < E_DIM; ++e) { lg[e] = expf(lg[e] - mx); Z += lg[e]; }
    const float inv = 1.0f / Z;
    #pragma unroll
    for (int e = 0; e < E_DIM; ++e) g8[(size_t)row * E_DIM + e] = lg[e] * inv;
  }
}

// ---------------- 128x128 4-wave, 2-slot dbuf, 3 blocks/CU, A2-fused epilogue ------
__global__ __launch_bounds__(256, 3) void k_gemm128(
    const unsigned short* __restrict__ A, long long lda,
    const unsigned short* __restrict__ B, long long ldb,
    int Ktot,
    const float* __restrict__ g8, const float* __restrict__ lam, int k_real,
    unsigned short* __restrict__ A2, int lda2) {
  __shared__ unsigned short lds[2 * 8192];   // 32 KiB: slot = A[128][32] + B[128][32]
  const int tid = threadIdx.x;
  const int lane = tid & 63;
  const int w = tid >> 6;            // 0..3
  const long long brow = (long long)blockIdx.x * 128;
  const long long bcol = (long long)blockIdx.y * 128;
  const int c0 = w * 2;
  const int sr0 = lane >> 2;
  const int sj  = lane & 3;
  const int l15 = lane & 15;
  const int jhi = lane >> 4;
  const int wr = (w >> 1) * 64;
  const int wc = (w & 1) * 64;

  auto stage = [&](int tt) {
    unsigned short* dstA = lds + (tt & 1) * 8192;
    #pragma unroll
    for (int c = 0; c < 2; ++c) {
      const int chunk = c0 + c;
      const int lrow = chunk * 16 + sr0;
      const int jj = sj ^ ((lrow >> 1) & 3);
      async_copy16(A + (brow + lrow) * lda + (long long)tt * 32 + jj * 8,
                   (void*)(dstA + chunk * 512));
      async_copy16(B + (bcol + lrow) * ldb + (long long)tt * 32 + jj * 8,
                   (void*)(dstA + 4096 + chunk * 512));
    }
  };

  f32x4 acc[4][4];
  #pragma unroll
  for (int m = 0; m < 4; ++m)
    #pragma unroll
    for (int n = 0; n < 4; ++n)
      #pragma unroll
      for (int j = 0; j < 4; ++j) acc[m][n][j] = 0.0f;

  const int NT = Ktot >> 5;
  stage(0);
  asm volatile("s_waitcnt vmcnt(0)" ::: "memory");
  __builtin_amdgcn_s_barrier();

  for (int t = 0; t < NT; ++t) {
    const unsigned short* Areg = lds + (t & 1) * 8192;
    const unsigned short* Breg = Areg + 4096;
    if (t + 1 < NT) stage(t + 1);
    short8 av[4], bv[4];
    #pragma unroll
    for (int m = 0; m < 4; ++m) {
      const int row = wr + m * 16 + l15;
      const int jj = jhi ^ ((row >> 1) & 3);
      av[m] = *(const short8*)(Areg + row * 32 + jj * 8);
    }
    #pragma unroll
    for (int n = 0; n < 4; ++n) {
      const int row = wc + n * 16 + l15;
      const int jj = jhi ^ ((row >> 1) & 3);
      bv[n] = *(const short8*)(Breg + row * 32 + jj * 8);
    }
    __builtin_amdgcn_s_setprio(1);
    #pragma unroll
    for (int m = 0; m < 4; ++m)
      #pragma unroll
      for (int n = 0; n < 4; ++n)
        acc[m][n] = __builtin_amdgcn_mfma_f32_16x16x32_bf16(av[m], bv[n], acc[m][n], 0, 0, 0);
    __builtin_amdgcn_s_setprio(0);
    asm volatile("s_waitcnt vmcnt(0)" ::: "memory");
    __builtin_amdgcn_s_barrier();
  }

  // epilogue: A2 = bf16(acc * coef), coef = sum_e g8[row,e]*lam[e,col]
  float lamE[E_DIM][4];
  #pragma unroll
  for (int n = 0; n < 4; ++n) {
    const long long col = bcol + wc + n * 16 + l15;
    #pragma unroll
    for (int e = 0; e < E_DIM; ++e)
      lamE[e][n] = (col < k_real) ? lam[(size_t)e * k_real + col] : 0.0f;
  }
  #pragma unroll
  for (int m = 0; m < 4; ++m) {
    float coef[4][4];   // [j][n]
    #pragma unroll
    for (int j = 0; j < 4; ++j)
      #pragma unroll
      for (int n = 0; n < 4; ++n) coef[j][n] = 0.0f;
    #pragma unroll
    for (int j = 0; j < 4; ++j) {
      const long long row = brow + wr + m * 16 + jhi * 4 + j;
      const float* gr = g8 + row * E_DIM;
      #pragma unroll
      for (int e = 0; e < E_DIM; ++e) {
        const float ge = gr[e];
        #pragma unroll
        for (int n = 0; n < 4; ++n) coef[j][n] += ge * lamE[e][n];
      }
    }
    #pragma unroll
    for (int n = 0; n < 4; ++n) {
      const long long col = bcol + wc + n * 16 + l15;
      #pragma unroll
      for (int j = 0; j < 4; ++j) {
        const long long row = brow + wr + m * 16 + jhi * 4 + j;
        A2[row * lda2 + col] = f2bf(acc[m][n][j] * coef[j][n]);
      }
    }
  }
}

// ---------------- 256x256 8-wave, 2-slot dbuf (64 KiB), 2 blocks/CU ---------------
// m97-pattern at 256^2 tile: body t = { stage(t+1) -> ds_read frags(t) -> 32 MFMA
// -> vmcnt(0) -> barrier }. Cross-block wave overlap (2 blocks/CU) hides the drain.
template<int EPI>
__global__ __launch_bounds__(512, 4) void k_gemm256(
    const unsigned short* __restrict__ A0, int lda0,
    const unsigned short* __restrict__ A1, int lda1,
    const unsigned short* __restrict__ B0, int ldb0,
    const unsigned short* __restrict__ B1, int ldb1,
    int ka0, int Ktot, int gridM,
    float* __restrict__ Cout, int ldc,
    const float* __restrict__ vcol) {
  __shared__ unsigned short lds[2 * 16384];   // 64 KiB
  const int tid = threadIdx.x;
  const int lane = tid & 63;
  const int w = tid >> 6;            // 0..7
  const int wm = w >> 2;             // 0..1  (M half)
  const int wn = w & 3;              // 0..3  (N quarter)

  // bijective XCD swizzle (grid size divisible by 8)
  int bid = blockIdx.x;
  const int cpx = gridDim.x >> 3;
  bid = (bid & 7) * cpx + (bid >> 3);
  const int bx = bid % gridM;
  const int by = bid / gridM;
  const long long brow = (long long)bx * 256;
  const long long bcol = (long long)by * 256;

  const int c0 = w * 2;
  const int sr0 = lane >> 2;
  const int sj  = lane & 3;
  const int l15 = lane & 15;
  const int jhi = lane >> 4;

  auto stage = [&](int tt) {
    const int k0 = tt * 32;
    const unsigned short* PA; long long ldA; long long kA;
    const unsigned short* PB; long long ldB; long long kB;
    if (k0 < ka0) { PA = A0; ldA = lda0; kA = k0;       PB = B0; ldB = ldb0; kB = k0; }
    else          { PA = A1; ldA = lda1; kA = k0 - ka0; PB = B1; ldB = ldb1; kB = k0 - ka0; }
    unsigned short* dst = lds + (tt & 1) * 16384;
    #pragma unroll
    for (int c = 0; c < 2; ++c) {
      const int chunk = c0 + c;
      const int lrow = chunk * 16 + sr0;
      const int jj = sj ^ ((lrow >> 1) & 3);
      async_copy16(PA + (brow + lrow) * ldA + kA + jj * 8, (void*)(dst + chunk * 512));
      async_copy16(PB + (bcol + lrow) * ldB + kB + jj * 8, (void*)(dst + 8192 + chunk * 512));
    }
  };

  f32x4 acc[8][4];
  #pragma unroll
  for (int m = 0; m < 8; ++m)
    #pragma unroll
    for (int n = 0; n < 4; ++n)
      #pragma unroll
      for (int j = 0; j < 4; ++j) acc[m][n][j] = 0.0f;

  const int NT = Ktot >> 5;
  stage(0);
  asm volatile("s_waitcnt vmcnt(0)" ::: "memory");
  __builtin_amdgcn_s_barrier();

  for (int t = 0; t < NT; ++t) {
    const unsigned short* Areg = lds + (t & 1) * 16384;
    const unsigned short* Breg = Areg + 8192;
    if (t + 1 < NT) stage(t + 1);
    short8 av[8], bv[4];
    #pragma unroll
    for (int m = 0; m < 8; ++m) {
      const int row = wm * 128 + m * 16 + l15;
      const int jj = jhi ^ ((row >> 1) & 3);
      av[m] = *(const short8*)(Areg + row * 32 + jj * 8);
    }
    #pragma unroll
    for (int n = 0; n < 4; ++n) {
      const int row = wn * 64 + n * 16 + l15;
      const int jj = jhi ^ ((row >> 1) & 3);
      bv[n] = *(const short8*)(Breg + row * 32 + jj * 8);
    }
    __builtin_amdgcn_s_setprio(1);
    #pragma unroll
    for (int m = 0; m < 8; ++m)
      #pragma unroll
      for (int n = 0; n < 4; ++n)
        acc[m][n] = __builtin_amdgcn_mfma_f32_16x16x32_bf16(av[m], bv[n], acc[m][n], 0, 0, 0);
    __builtin_amdgcn_s_setprio(0);
    asm volatile("s_waitcnt vmcnt(0)" ::: "memory");
    __builtin_amdgcn_s_barrier();
  }

  // epilogue: C/D layout col = lane&15, row = (lane>>4)*4 + j ; out *= (1+v[col])
  #pragma unroll
  for (int m = 0; m < 8; ++m) {
    #pragma unroll
    for (int n = 0; n < 4; ++n) {
      const long long col = bcol + wn * 64 + n * 16 + l15;
      float cs = 1.0f;
      if (EPI == 1) cs = 1.0f + vcol[col];
      #pragma unroll
      for (int j = 0; j < 4; ++j) {
        const long long row = brow + wm * 128 + m * 16 + jhi * 4 + j;
        Cout[row * ldc + col] = acc[m][n][j] * cs;
      }
    }
  }
}

extern "C" void kernel_launch(void* const* d_in, const int* in_sizes, int n_in,
                              void* d_out, int out_size, void* d_ws, size_t ws_size,
                              hipStream_t stream) {
  const float* x   = (const float*)d_in[0];
  const float* W   = (const float*)d_in[1];
  const float* U   = (const float*)d_in[2];
  const float* V   = (const float*)d_in[3];
  const float* lam = (const float*)d_in[4];
  const float* v   = (const float*)d_in[5];
  const float* Wg1 = (const float*)d_in[6];
  const float* Wg2 = (const float*)d_in[7];
  float* out = (float*)d_out;

  const int N = in_sizes[0] / D_DIM;        // 16384
  const int k = in_sizes[2] / D_DIM;        // SVD rank (~566)
  const int k_pad = (k + 127) & ~127;       // A2/Vb column stride (640)
  const int kq    = (k + 63) & ~63;         // K-extent actually used by gemm256 (576)

  char* ws = (char*)d_ws;
  size_t off = 0;
  auto alloc = [&](size_t bytes) -> void* {
    void* p = ws + off;
    off += (bytes + 255) & ~(size_t)255;
    return p;
  };
  unsigned short* xb  = (unsigned short*)alloc((size_t)N * D_DIM * 2);
  unsigned short* Wt  = (unsigned short*)alloc((size_t)D_DIM * D_DIM * 2);
  unsigned short* Ukt = (unsigned short*)alloc((size_t)k_pad * D_DIM * 2);
  unsigned short* Vb  = (unsigned short*)alloc((size_t)D_DIM * k_pad * 2);
  unsigned short* A2  = (unsigned short*)alloc((size_t)N * k_pad * 2);
  float*          u1  = (float*)alloc((size_t)D_DIM * 4);
  float*          g8  = (float*)alloc((size_t)N * E_DIM * 4);
  if (off > ws_size) return;

  // 1) tiny routing precompute, then fused convert+gate
  k_u1<<<D_DIM / 4, 256, 0, stream>>>(U, Wg1, u1, D_DIM, k);
  k_cvtgate<<<N / 4, 256, 0, stream>>>(x, xb, u1, Wg2, g8, N);
  k_transpose_bf16<<<dim3(D_DIM / 32, D_DIM / 32), dim3(32, 8), 0, stream>>>(
      W, D_DIM, D_DIM, D_DIM, Wt, D_DIM);
  k_transpose_bf16<<<dim3(k_pad / 32, D_DIM / 32), dim3(32, 8), 0, stream>>>(
      U, D_DIM, k, k, Ukt, k_pad);
  k_pad_bf16<<<512, 256, 0, stream>>>(V, Vb, D_DIM, k, k_pad);

  // 2) xu GEMM with fused routing epilogue -> A2 = bf16((xb@Ukt^T) * (g8@lam))
  k_gemm128<<<dim3(N / 128, k_pad / 128), 256, 0, stream>>>(
      xb, D_DIM, Ukt, D_DIM, D_DIM, g8, lam, k, A2, k_pad);

  // 3) fused GEMM: out = (xb@Wt^T + A2@Vb^T) * (1+v)   [2-slot, 2 blocks/CU]
  const int gridM = N / 256;                 // 64
  const int gridN = D_DIM / 256;             // 8
  k_gemm256<1><<<gridM * gridN, 512, 0, stream>>>(
      xb, D_DIM, A2, k_pad,
      Wt, D_DIM, Vb, k_pad,
      D_DIM, D_DIM + kq, gridM,
      out, D_DIM, v);
}

// Round 14
// 308.144 us; speedup vs baseline: 5.8155x; 5.8155x over previous
//
#include <hip/hip_runtime.h>
#include <hip/hip_bf16.h>

#define D_DIM 2048
#define E_DIM 8

typedef __attribute__((ext_vector_type(8))) short short8;
typedef __attribute__((ext_vector_type(4))) float f32x4;

__device__ __forceinline__ unsigned short f2bf(float f) {
  union { float f; unsigned int u; } v; v.f = f;
  unsigned int u = v.u;
  u += 0x7FFFu + ((u >> 16) & 1u);   // round-to-nearest-even
  return (unsigned short)(u >> 16);
}

__device__ __forceinline__ void async_copy16(const void* g, void* l) {
  __builtin_amdgcn_global_load_lds((const __attribute__((address_space(1))) void*)g,
                                   (__attribute__((address_space(3))) void*)l,
                                   16, 0, 0);
}

// ---------------- transpose f32 -> bf16 (with zero pad) ----------------
__global__ void k_transpose_bf16(const float* __restrict__ in, int in_rows, int in_cols,
                                 int in_ld, unsigned short* __restrict__ out, int out_rows) {
  __shared__ float tile[32][33];
  const int tx = threadIdx.x;  // 0..31
  const int ty = threadIdx.y;  // 0..7
  const int c = blockIdx.x * 32 + tx;
  #pragma unroll
  for (int i = 0; i < 4; ++i) {
    const int r = blockIdx.y * 32 + ty + i * 8;
    float vv = 0.0f;
    if (r < in_rows && c < in_cols) vv = in[(size_t)r * in_ld + c];
    tile[ty + i * 8][tx] = vv;
  }
  __syncthreads();
  const int oc = blockIdx.y * 32 + tx;   // = original row
  #pragma unroll
  for (int i = 0; i < 4; ++i) {
    const int orow = blockIdx.x * 32 + ty + i * 8;  // = original col (padded)
    if (orow < out_rows && oc < in_rows)
      out[(size_t)orow * in_rows + oc] = f2bf(tile[tx][ty + i * 8]);
  }
}

// ---------------- pad-copy f32 -> bf16 (row-major, pad cols with 0) ----------------
__global__ void k_pad_bf16(const float* __restrict__ in, unsigned short* __restrict__ out,
                           int rows, int cols, int cols_pad) {
  long long idx = (long long)blockIdx.x * blockDim.x + threadIdx.x;
  const long long total = (long long)rows * cols_pad;
  const long long stride = (long long)gridDim.x * blockDim.x;
  for (; idx < total; idx += stride) {
    const int r = (int)(idx / cols_pad);
    const int c = (int)(idx % cols_pad);
    out[idx] = (c < cols) ? f2bf(in[(size_t)r * cols + c]) : (unsigned short)0;
  }
}

// ---------------- u1 = U @ Wg1  (f32, one wave per output row d) ----------------
__global__ void k_u1(const float* __restrict__ U, const float* __restrict__ Wg1,
                     float* __restrict__ u1, int D, int k) {
  const int w = threadIdx.x >> 6;
  const int lane = threadIdx.x & 63;
  const int d = blockIdx.x * 4 + w;
  if (d >= D) return;
  const float* row = U + (size_t)d * k;
  float s = 0.0f;
  for (int j = lane; j < k; j += 64) s += row[j] * Wg1[j];
  #pragma unroll
  for (int off = 32; off; off >>= 1) s += __shfl_xor(s, off);
  if (lane == 0) u1[d] = s;
}

// ---------------- fused cvt+gate: xb = bf16(x); g8 = softmax((x.u1)*Wg2) ----------
__global__ void k_cvtgate(const float* __restrict__ x,
                          unsigned short* __restrict__ xb,
                          const float* __restrict__ u1, const float* __restrict__ Wg2,
                          float* __restrict__ g8, int Nrows) {
  const int w = threadIdx.x >> 6;
  const int lane = threadIdx.x & 63;
  const int row = blockIdx.x * 4 + w;
  if (row >= Nrows) return;
  const float* xr = x + (size_t)row * D_DIM;
  unsigned short* xo = xb + (size_t)row * D_DIM;
  float s = 0.0f;
  #pragma unroll
  for (int t = 0; t < D_DIM / 512; ++t) {
    const int base = (t * 64 + lane) * 8;
    float4 a = *(const float4*)(xr + base);
    float4 b = *(const float4*)(xr + base + 4);
    float4 ua = *(const float4*)(u1 + base);
    float4 ub = *(const float4*)(u1 + base + 4);
    s += a.x * ua.x + a.y * ua.y + a.z * ua.z + a.w * ua.w +
         b.x * ub.x + b.y * ub.y + b.z * ub.z + b.w * ub.w;
    short8 r;
    r[0] = (short)f2bf(a.x); r[1] = (short)f2bf(a.y);
    r[2] = (short)f2bf(a.z); r[3] = (short)f2bf(a.w);
    r[4] = (short)f2bf(b.x); r[5] = (short)f2bf(b.y);
    r[6] = (short)f2bf(b.z); r[7] = (short)f2bf(b.w);
    *(short8*)(xo + base) = r;
  }
  #pragma unroll
  for (int off = 32; off; off >>= 1) s += __shfl_xor(s, off);
  if (lane == 0) {
    float lg[E_DIM], mx = -INFINITY;
    #pragma unroll
    for (int e = 0; e < E_DIM; ++e) { lg[e] = s * Wg2[e]; mx = fmaxf(mx, lg[e]); }
    float Z = 0.0f;
    #pragma unroll
    for (int e = 0; e < E_DIM; ++e) { lg[e] = expf(lg[e] - mx); Z += lg[e]; }
    const float inv = 1.0f / Z;
    #pragma unroll
    for (int e = 0; e < E_DIM; ++e) g8[(size_t)row * E_DIM + e] = lg[e] * inv;
  }
}

// ---------------- 128x128 4-wave, 2-slot dbuf, 3 blocks/CU, A2-fused epilogue ------
__global__ __launch_bounds__(256, 3) void k_gemm128(
    const unsigned short* __restrict__ A, long long lda,
    const unsigned short* __restrict__ B, long long ldb,
    int Ktot,
    const float* __restrict__ g8, const float* __restrict__ lam, int k_real,
    unsigned short* __restrict__ A2, int lda2) {
  __shared__ unsigned short lds[2 * 8192];   // 32 KiB: slot = A[128][32] + B[128][32]
  const int tid = threadIdx.x;
  const int lane = tid & 63;
  const int w = tid >> 6;            // 0..3
  const long long brow = (long long)blockIdx.x * 128;
  const long long bcol = (long long)blockIdx.y * 128;
  const int c0 = w * 2;
  const int sr0 = lane >> 2;
  const int sj  = lane & 3;
  const int l15 = lane & 15;
  const int jhi = lane >> 4;
  const int wr = (w >> 1) * 64;
  const int wc = (w & 1) * 64;

  auto stage = [&](int tt) {
    unsigned short* dstA = lds + (tt & 1) * 8192;
    #pragma unroll
    for (int c = 0; c < 2; ++c) {
      const int chunk = c0 + c;
      const int lrow = chunk * 16 + sr0;
      const int jj = sj ^ ((lrow >> 1) & 3);
      async_copy16(A + (brow + lrow) * lda + (long long)tt * 32 + jj * 8,
                   (void*)(dstA + chunk * 512));
      async_copy16(B + (bcol + lrow) * ldb + (long long)tt * 32 + jj * 8,
                   (void*)(dstA + 4096 + chunk * 512));
    }
  };

  f32x4 acc[4][4];
  #pragma unroll
  for (int m = 0; m < 4; ++m)
    #pragma unroll
    for (int n = 0; n < 4; ++n)
      #pragma unroll
      for (int j = 0; j < 4; ++j) acc[m][n][j] = 0.0f;

  const int NT = Ktot >> 5;
  stage(0);
  asm volatile("s_waitcnt vmcnt(0)" ::: "memory");
  __builtin_amdgcn_s_barrier();

  for (int t = 0; t < NT; ++t) {
    const unsigned short* Areg = lds + (t & 1) * 8192;
    const unsigned short* Breg = Areg + 4096;
    if (t + 1 < NT) stage(t + 1);
    short8 av[4], bv[4];
    #pragma unroll
    for (int m = 0; m < 4; ++m) {
      const int row = wr + m * 16 + l15;
      const int jj = jhi ^ ((row >> 1) & 3);
      av[m] = *(const short8*)(Areg + row * 32 + jj * 8);
    }
    #pragma unroll
    for (int n = 0; n < 4; ++n) {
      const int row = wc + n * 16 + l15;
      const int jj = jhi ^ ((row >> 1) & 3);
      bv[n] = *(const short8*)(Breg + row * 32 + jj * 8);
    }
    __builtin_amdgcn_s_setprio(1);
    #pragma unroll
    for (int m = 0; m < 4; ++m)
      #pragma unroll
      for (int n = 0; n < 4; ++n)
        acc[m][n] = __builtin_amdgcn_mfma_f32_16x16x32_bf16(av[m], bv[n], acc[m][n], 0, 0, 0);
    __builtin_amdgcn_s_setprio(0);
    asm volatile("s_waitcnt vmcnt(0)" ::: "memory");
    __builtin_amdgcn_s_barrier();
  }

  // epilogue: A2 = bf16(acc * coef), coef = sum_e g8[row,e]*lam[e,col]
  float lamE[E_DIM][4];
  #pragma unroll
  for (int n = 0; n < 4; ++n) {
    const long long col = bcol + wc + n * 16 + l15;
    #pragma unroll
    for (int e = 0; e < E_DIM; ++e)
      lamE[e][n] = (col < k_real) ? lam[(size_t)e * k_real + col] : 0.0f;
  }
  #pragma unroll
  for (int m = 0; m < 4; ++m) {
    float coef[4][4];   // [j][n]
    #pragma unroll
    for (int j = 0; j < 4; ++j)
      #pragma unroll
      for (int n = 0; n < 4; ++n) coef[j][n] = 0.0f;
    #pragma unroll
    for (int j = 0; j < 4; ++j) {
      const long long row = brow + wr + m * 16 + jhi * 4 + j;
      const float* gr = g8 + row * E_DIM;
      #pragma unroll
      for (int e = 0; e < E_DIM; ++e) {
        const float ge = gr[e];
        #pragma unroll
        for (int n = 0; n < 4; ++n) coef[j][n] += ge * lamE[e][n];
      }
    }
    #pragma unroll
    for (int n = 0; n < 4; ++n) {
      const long long col = bcol + wc + n * 16 + l15;
      #pragma unroll
      for (int j = 0; j < 4; ++j) {
        const long long row = brow + wr + m * 16 + jhi * 4 + j;
        A2[row * lda2 + col] = f2bf(acc[m][n][j] * coef[j][n]);
      }
    }
  }
}

// ---------------- 256x256 8-wave, 4-slot rotation, reg-double-buffered (best) ------
template<int EPI>
__global__ __launch_bounds__(512, 2) void k_gemm256(
    const unsigned short* __restrict__ A0, int lda0,
    const unsigned short* __restrict__ A1, int lda1,
    const unsigned short* __restrict__ B0, int ldb0,
    const unsigned short* __restrict__ B1, int ldb1,
    int ka0, int Ktot, int gridM,
    float* __restrict__ Cout, int ldc,
    const float* __restrict__ vcol) {
  __shared__ unsigned short lds[4 * 16384];   // 128 KiB
  const int tid = threadIdx.x;
  const int lane = tid & 63;
  const int w = tid >> 6;            // 0..7
  const int wm = w >> 2;             // 0..1  (M half)
  const int wn = w & 3;              // 0..3  (N quarter)

  // bijective XCD swizzle (grid size divisible by 8)
  int bid = blockIdx.x;
  const int cpx = gridDim.x >> 3;
  bid = (bid & 7) * cpx + (bid >> 3);
  const int bx = bid % gridM;
  const int by = bid / gridM;
  const long long brow = (long long)bx * 256;
  const long long bcol = (long long)by * 256;

  const int c0 = w * 2;
  const int sr0 = lane >> 2;
  const int sj  = lane & 3;
  const int l15 = lane & 15;
  const int jhi = lane >> 4;

  auto stage = [&](int tt) {
    const int k0 = tt * 32;
    const unsigned short* PA; long long ldA; long long kA;
    const unsigned short* PB; long long ldB; long long kB;
    if (k0 < ka0) { PA = A0; ldA = lda0; kA = k0;       PB = B0; ldB = ldb0; kB = k0; }
    else          { PA = A1; ldA = lda1; kA = k0 - ka0; PB = B1; ldB = ldb1; kB = k0 - ka0; }
    unsigned short* dst = lds + (tt & 3) * 16384;
    #pragma unroll
    for (int c = 0; c < 2; ++c) {
      const int chunk = c0 + c;
      const int lrow = chunk * 16 + sr0;
      const int jj = sj ^ ((lrow >> 1) & 3);
      async_copy16(PA + (brow + lrow) * ldA + kA + jj * 8, (void*)(dst + chunk * 512));
      async_copy16(PB + (bcol + lrow) * ldB + kB + jj * 8, (void*)(dst + 8192 + chunk * 512));
    }
  };

  auto load_frags = [&](int tt, short8* av, short8* bv) {
    const unsigned short* Areg = lds + (tt & 3) * 16384;
    const unsigned short* Breg = Areg + 8192;
    #pragma unroll
    for (int m = 0; m < 8; ++m) {
      const int row = wm * 128 + m * 16 + l15;
      const int jj = jhi ^ ((row >> 1) & 3);
      av[m] = *(const short8*)(Areg + row * 32 + jj * 8);
    }
    #pragma unroll
    for (int n = 0; n < 4; ++n) {
      const int row = wn * 64 + n * 16 + l15;
      const int jj = jhi ^ ((row >> 1) & 3);
      bv[n] = *(const short8*)(Breg + row * 32 + jj * 8);
    }
  };

  f32x4 acc[8][4];
  #pragma unroll
  for (int m = 0; m < 8; ++m)
    #pragma unroll
    for (int n = 0; n < 4; ++n)
      #pragma unroll
      for (int j = 0; j < 4; ++j) acc[m][n][j] = 0.0f;

  auto do_mfma = [&](short8* av, short8* bv) {
    __builtin_amdgcn_s_setprio(1);
    #pragma unroll
    for (int m = 0; m < 8; ++m)
      #pragma unroll
      for (int n = 0; n < 4; ++n)
        acc[m][n] = __builtin_amdgcn_mfma_f32_16x16x32_bf16(av[m], bv[n], acc[m][n], 0, 0, 0);
    __builtin_amdgcn_s_setprio(0);
  };

  const int NT = Ktot >> 5;   // even (Ktot multiple of 64)
  stage(0); stage(1); stage(2);
  asm volatile("s_waitcnt vmcnt(4)" ::: "memory");   // tiles 0,1 landed
  __builtin_amdgcn_s_barrier();

  short8 avA[8], bvA[4], avB[8], bvB[4];
  load_frags(0, avA, bvA);

  for (int t = 0; t < NT; t += 2) {
    // body t: compute set A, read tile t+1 into set B
    if (t + 3 < NT) stage(t + 3);
    load_frags(t + 1, avB, bvB);
    do_mfma(avA, bvA);
    asm volatile("s_waitcnt vmcnt(4)" ::: "memory");
    __builtin_amdgcn_s_barrier();
    // body t+1: compute set B, read tile t+2 into set A
    if (t + 4 < NT) stage(t + 4);
    if (t + 2 < NT) load_frags(t + 2, avA, bvA);
    do_mfma(avB, bvB);
    asm volatile("s_waitcnt vmcnt(4)" ::: "memory");
    __builtin_amdgcn_s_barrier();
  }

  // epilogue: C/D layout col = lane&15, row = (lane>>4)*4 + j ; out *= (1+v[col])
  #pragma unroll
  for (int m = 0; m < 8; ++m) {
    #pragma unroll
    for (int n = 0; n < 4; ++n) {
      const long long col = bcol + wn * 64 + n * 16 + l15;
      float cs = 1.0f;
      if (EPI == 1) cs = 1.0f + vcol[col];
      #pragma unroll
      for (int j = 0; j < 4; ++j) {
        const long long row = brow + wm * 128 + m * 16 + jhi * 4 + j;
        Cout[row * ldc + col] = acc[m][n][j] * cs;
      }
    }
  }
}

extern "C" void kernel_launch(void* const* d_in, const int* in_sizes, int n_in,
                              void* d_out, int out_size, void* d_ws, size_t ws_size,
                              hipStream_t stream) {
  const float* x   = (const float*)d_in[0];
  const float* W   = (const float*)d_in[1];
  const float* U   = (const float*)d_in[2];
  const float* V   = (const float*)d_in[3];
  const float* lam = (const float*)d_in[4];
  const float* v   = (const float*)d_in[5];
  const float* Wg1 = (const float*)d_in[6];
  const float* Wg2 = (const float*)d_in[7];
  float* out = (float*)d_out;

  const int N = in_sizes[0] / D_DIM;        // 16384
  const int k = in_sizes[2] / D_DIM;        // SVD rank (~566)
  const int k_pad = (k + 127) & ~127;       // A2/Vb column stride (640)
  const int kq    = (k + 63) & ~63;         // K-extent actually used by gemm256 (576)

  char* ws = (char*)d_ws;
  size_t off = 0;
  auto alloc = [&](size_t bytes) -> void* {
    void* p = ws + off;
    off += (bytes + 255) & ~(size_t)255;
    return p;
  };
  unsigned short* xb  = (unsigned short*)alloc((size_t)N * D_DIM * 2);
  unsigned short* Wt  = (unsigned short*)alloc((size_t)D_DIM * D_DIM * 2);
  unsigned short* Ukt = (unsigned short*)alloc((size_t)k_pad * D_DIM * 2);
  unsigned short* Vb  = (unsigned short*)alloc((size_t)D_DIM * k_pad * 2);
  unsigned short* A2  = (unsigned short*)alloc((size_t)N * k_pad * 2);
  float*          u1  = (float*)alloc((size_t)D_DIM * 4);
  float*          g8  = (float*)alloc((size_t)N * E_DIM * 4);
  if (off > ws_size) return;

  // 1) tiny routing precompute, then fused convert+gate
  k_u1<<<D_DIM / 4, 256, 0, stream>>>(U, Wg1, u1, D_DIM, k);
  k_cvtgate<<<N / 4, 256, 0, stream>>>(x, xb, u1, Wg2, g8, N);
  k_transpose_bf16<<<dim3(D_DIM / 32, D_DIM / 32), dim3(32, 8), 0, stream>>>(
      W, D_DIM, D_DIM, D_DIM, Wt, D_DIM);
  k_transpose_bf16<<<dim3(k_pad / 32, D_DIM / 32), dim3(32, 8), 0, stream>>>(
      U, D_DIM, k, k, Ukt, k_pad);
  k_pad_bf16<<<512, 256, 0, stream>>>(V, Vb, D_DIM, k, k_pad);

  // 2) xu GEMM with fused routing epilogue -> A2 = bf16((xb@Ukt^T) * (g8@lam))
  k_gemm128<<<dim3(N / 128, k_pad / 128), 256, 0, stream>>>(
      xb, D_DIM, Ukt, D_DIM, D_DIM, g8, lam, k, A2, k_pad);

  // 3) fused GEMM: out = (xb@Wt^T + A2@Vb^T) * (1+v)
  //    K = 2048 + kq (A2/Vb cols [k, kq) are zero; stride stays k_pad)
  const int gridM = N / 256;                 // 64
  const int gridN = D_DIM / 256;             // 8
  k_gemm256<1><<<gridM * gridN, 512, 0, stream>>>(
      xb, D_DIM, A2, k_pad,
      Wt, D_DIM, Vb, k_pad,
      D_DIM, D_DIM + kq, gridM,
      out, D_DIM, v);
}